// Round 18
// baseline (266.789 us; speedup 1.0000x reference)
//
#include <hip/hip_runtime.h>
#include <cstdint>

// ---------------------------------------------------------------------------
// NEO vision embeddings, MI355X (gfx950) — round 18: patch stages A as RAW
// f32 via global_load_lds (no pixf buffer, no reg-staging); f32->f16 cvt in
// the fragment-read path. BK=32, single 48KB slot, 2 blocks/CU. dense r9.
//   conv:  B1 f16 [1024][608] (zero-pad k>=588), B2 f16 perm [2048][4096]
//   GEMM1: peM = merge(rope(gelu(pix @ B1^T + b1)))  (256^2, BK=32, 19 iters)
//   GEMM2: out = peM[8192,4096] @ B2^T + b2          (256^2 BK=64, r9)
// A LDS: [256 rows][128B f32], slot = c ^ (row&7)  (8 chunks of 16B)
// B LDS: [256 rows][64B f16],  slot = c ^ (row&3)  (4 chunks of 16B)
// K-tail: A garbage (clamped loads) x B zero-pad = 0 contribution.
// ---------------------------------------------------------------------------

using f16x8 = __attribute__((ext_vector_type(8))) _Float16;
using f32x4 = __attribute__((ext_vector_type(4))) float;

__device__ __forceinline__ void gload_lds16(const void* g, void* l) {
  __builtin_amdgcn_global_load_lds(
      reinterpret_cast<const __attribute__((address_space(1))) unsigned int*>(
          reinterpret_cast<uintptr_t>(g)),
      reinterpret_cast<__attribute__((address_space(3))) unsigned int*>(
          reinterpret_cast<uintptr_t>(l)),
      16, 0, 0);
}

#define BAR   asm volatile("s_barrier" ::: "memory")
#define LGKM0 asm volatile("s_waitcnt lgkmcnt(0)" ::: "memory")
#define VM0   asm volatile("s_waitcnt vmcnt(0)" ::: "memory")

#define KP1 608   // padded K for GEMM1 (588 -> 608 = 19 x 32)

// -------------------------- weight conversion ------------------------------

__global__ void conv_w_kernel(const float* __restrict__ w1,
                              const float* __restrict__ w2,
                              _Float16* __restrict__ h1,
                              _Float16* __restrict__ h2) {
  const int bid = blockIdx.x;
  if (bid < 2432) {                                // b1: 1024*608
    int i = bid * 256 + threadIdx.x;
    int e = i / KP1;
    int k = i - e * KP1;
    float v = (k < 588) ? w1[(size_t)e * 588 + k] : 0.0f;
    h1[i] = (_Float16)v;
  } else {                                         // b2: 2048*1024 float4s
    int j = (bid - 2432) * 256 + threadIdx.x;
    int o = j >> 10;
    int e = j & 1023;
    const float4 v = *(const float4*)(w2 + (size_t)o * 4096 + e * 4);
    h2[(size_t)o * 4096 + e]        = (_Float16)v.x;
    h2[(size_t)o * 4096 + 1024 + e] = (_Float16)v.y;
    h2[(size_t)o * 4096 + 2048 + e] = (_Float16)v.z;
    h2[(size_t)o * 4096 + 3072 + e] = (_Float16)v.w;
  }
}

// ------------------------- dense GEMM body macros --------------------------

#define MFMA16(I0, J0, AV, BV)                                                \
  _Pragma("unroll") for (int i_ = 0; i_ < 4; ++i_)                            \
  _Pragma("unroll") for (int j_ = 0; j_ < 2; ++j_)                            \
  _Pragma("unroll") for (int k_ = 0; k_ < 2; ++k_)                            \
      acc[(I0) + i_][(J0) + j_] = __builtin_amdgcn_mfma_f32_16x16x32_f16(     \
          AV[i_][k_], BV[j_][k_], acc[(I0) + i_][(J0) + j_], 0, 0, 0);

#define TILE_BODY(sb)                                                         \
  {                                                                           \
    f16x8 a0[4][2], a1[4][2], vb0[2][2], vb1[2][2];                           \
    _Pragma("unroll") for (int i = 0; i < 4; ++i) {                           \
      a0[i][0] = *(const f16x8*)(lbase + (sb) + aoff + i * 2048 + so0);       \
      a0[i][1] = *(const f16x8*)(lbase + (sb) + aoff + i * 2048 + so1);       \
    }                                                                         \
    _Pragma("unroll") for (int j = 0; j < 2; ++j) {                           \
      vb0[j][0] = *(const f16x8*)(lbase + (sb) + boff + j * 2048 + so0);      \
      vb0[j][1] = *(const f16x8*)(lbase + (sb) + boff + j * 2048 + so1);      \
    }                                                                         \
    MFMA16(0, 0, a0, vb0);                                                    \
    _Pragma("unroll") for (int j = 0; j < 2; ++j) {                           \
      vb1[j][0] = *(const f16x8*)(lbase + (sb) + boff + (2+j) * 2048 + so0);  \
      vb1[j][1] = *(const f16x8*)(lbase + (sb) + boff + (2+j) * 2048 + so1);  \
    }                                                                         \
    MFMA16(0, 2, a0, vb1);                                                    \
    _Pragma("unroll") for (int i = 0; i < 4; ++i) {                           \
      a1[i][0] = *(const f16x8*)(lbase + (sb) + aoff + (4+i) * 2048 + so0);   \
      a1[i][1] = *(const f16x8*)(lbase + (sb) + aoff + (4+i) * 2048 + so1);   \
    }                                                                         \
    MFMA16(4, 2, a1, vb1);                                                    \
    MFMA16(4, 0, a1, vb0);                                                    \
  }

// ---------- GEMM1: 256^2, BK=32, A f32 via gload_lds, 48KB slot ------------

__global__ __launch_bounds__(512, 2) void patch_gemm18(
    const float* __restrict__ pix,
    const _Float16* __restrict__ b1w,   // [1024][608], zeros for k>=588
    const float* __restrict__ bias1,
    const float* __restrict__ cosx, const float* __restrict__ sinx,
    const float* __restrict__ cosy, const float* __restrict__ siny,
    _Float16* __restrict__ peM)
{
  __shared__ char lds[49152];   // A f32 32KB | B f16 16KB (single slot)

  const int tid  = threadIdx.x;
  const int lane = tid & 63;
  const int wave = tid >> 6;
  const int wm = wave >> 2, wn = wave & 3;
  const int bm = blockIdx.x, bn = blockIdx.y;
  const int l15 = lane & 15;
  const int g   = lane >> 4;
  const int s7  = l15 & 7;

  const char* lbase = lds;
  char*       lw    = lds;

  const int bm256 = bm * 256, bn256 = bn * 256;
  // staging geometry
  const int arow = wave * 32 + (lane >> 3);   // A: 8 rows/instr, chunk=lane&7
  const int ac   = lane & 7;
  const int brow = wave * 32 + (lane >> 2);   // B: 16 rows/instr, chunk=lane&3
  const int bc   = lane & 3;
  const size_t PIXB = (size_t)32768 * 588 * 4;

  // fragment-read geometry
  const unsigned aB   = (unsigned)(wm * 16384 + l15 * 128);
  const unsigned soA0 = (unsigned)(((2 * g) ^ s7) * 16);
  const unsigned soA1 = soA0 ^ 16u;
  const unsigned bB   = (unsigned)(32768 + wn * 4096 + l15 * 64);
  const unsigned soB  = (unsigned)((g ^ (l15 & 3)) * 16);

  auto STAGE = [&](int s) {
#pragma unroll
    for (int u = 0; u < 4; ++u) {             // A (f32)
      const int row  = arow + u * 8;
      const int gcol = ac ^ (row & 7);
      size_t ob = (size_t)(bm256 + row) * 2352 + (size_t)s * 128 + gcol * 16;
      if (ob > PIXB - 16) ob = PIXB - 16;     // tail clamp (B zero-pad fixes)
      gload_lds16((const char*)pix + ob, lw + (wave * 4 + u) * 1024);
    }
#pragma unroll
    for (int u = 0; u < 2; ++u) {             // B (f16)
      const int row  = brow + u * 16;
      const int gcol = bc ^ (row & 3);
      gload_lds16(b1w + (size_t)(bn256 + row) * KP1 + s * 32 + gcol * 8,
                  lw + 32768 + (wave * 2 + u) * 1024);
    }
  };

  f32x4 acc[8][4] = {};

  for (int s = 0; s < 19; ++s) {
    STAGE(s);
    VM0; BAR;
    __builtin_amdgcn_s_setprio(1);
    f16x8 bf[4];
#pragma unroll
    for (int j = 0; j < 4; ++j)
      bf[j] = *(const f16x8*)(lbase + bB + j * 1024 + soB);
#pragma unroll
    for (int i = 0; i < 8; ++i) {
      const f32x4 lo = *(const f32x4*)(lbase + aB + i * 2048 + soA0);
      const f32x4 hi = *(const f32x4*)(lbase + aB + i * 2048 + soA1);
      f16x8 af;
#pragma unroll
      for (int q = 0; q < 4; ++q) {
        af[q]     = (_Float16)lo[q];
        af[4 + q] = (_Float16)hi[q];
      }
#pragma unroll
      for (int j = 0; j < 4; ++j)
        acc[i][j] = __builtin_amdgcn_mfma_f32_16x16x32_f16(af, bf[j],
                                                           acc[i][j], 0, 0, 0);
    }
    __builtin_amdgcn_s_setprio(0);
    LGKM0; BAR;
  }

  // ---- epilogue: per-wave LDS transpose (r17 exact; 33.3KB <= 48KB) -------
  float* sw = (float*)(lw) + wave * (16 * 65);
  const int md = (lane >> 4) * 4;
  const int rq = lane & 3;          // e-quarter
  const int lr = lane >> 2;         // row within 16-group
#pragma unroll
  for (int p = 0; p < 8; ++p) {
#pragma unroll
    for (int r = 0; r < 4; ++r) {
      const int lrow = md + r;
#pragma unroll
      for (int nf = 0; nf < 4; ++nf)
        sw[lrow * 65 + nf * 16 + l15] = acc[p][nf][r];
    }
    {
      const int m   = bm256 + wm * 128 + p * 16 + lr;
      const int pid = m & 4095;
      const int yy = pid >> 6, xx = pid & 63;
      const int t  = (m >> 12) * 1024 + (yy >> 1) * 32 + (xx >> 1);
      const int pq = (yy & 1) * 2 + (xx & 1);
      const int e0 = bn256 + wn * 64 + rq * 16;
      const int h2 = (e0 >= 512) ? 1 : 0;
      const int idx0 = (h2 ? (e0 - 512) : e0) >> 1;      // mult of 8
      const int pos  = h2 ? yy : xx;
      const float* ct = (h2 ? cosy : cosx) + pos * 256 + idx0;
      const float* st = (h2 ? siny : sinx) + pos * 256 + idx0;
      const float4 c0 = *(const float4*)ct, c1 = *(const float4*)(ct + 4);
      const float4 s0 = *(const float4*)st, s1 = *(const float4*)(st + 4);
      const float4 b0 = *(const float4*)(bias1 + e0);
      const float4 b1 = *(const float4*)(bias1 + e0 + 4);
      const float4 b2 = *(const float4*)(bias1 + e0 + 8);
      const float4 b3 = *(const float4*)(bias1 + e0 + 12);
      const float bb[16] = {b0.x,b0.y,b0.z,b0.w, b1.x,b1.y,b1.z,b1.w,
                            b2.x,b2.y,b2.z,b2.w, b3.x,b3.y,b3.z,b3.w};
      float v[16];
#pragma unroll
      for (int j = 0; j < 16; ++j) {
        float x = sw[lr * 65 + rq * 16 + j] + bb[j];
        v[j] = 0.5f * x * (1.0f + erff(x * 0.70710678118654752f));
      }
      const float cc[8] = {c0.x,c0.y,c0.z,c0.w, c1.x,c1.y,c1.z,c1.w};
      const float ss[8] = {s0.x,s0.y,s0.z,s0.w, s1.x,s1.y,s1.z,s1.w};
      _Float16 o[16];
#pragma unroll
      for (int k = 0; k < 8; ++k) {
        o[2*k]   = (_Float16)(v[2*k] * cc[k] - v[2*k+1] * ss[k]);
        o[2*k+1] = (_Float16)(v[2*k] * ss[k] + v[2*k+1] * cc[k]);
      }
      _Float16* dst = peM + (size_t)t * 4096 + pq * 1024 + e0;
      *(f16x8*)dst       = *(const f16x8*)&o[0];
      *(f16x8*)(dst + 8) = *(const f16x8*)&o[8];
    }
  }
}

// ------------------- GEMM2: r9 exact (127.5 us, MfmaUtil 50%) --------------

__global__ __launch_bounds__(512, 2) void dense_gemm9(
    const _Float16* __restrict__ aM,    // [8192][4096] merged pe
    const _Float16* __restrict__ bM,    // [2048][4096] permuted w2
    const float* __restrict__ bias2, float* __restrict__ out)
{
  __shared__ _Float16 lds[2][2][256][64];   // 128 KiB

  const int tid  = threadIdx.x;
  const int lane = tid & 63;
  const int wave = tid >> 6;
  const int wm = wave >> 2, wn = wave & 3;
  const int bm = blockIdx.x, bn = blockIdx.y;
  const int l15 = lane & 15;
  const int g   = lane >> 4;
  const int s7  = l15 & 7;

  const char* lbase = (const char*)lds;
  char*       lw    = (char*)lds;
  const unsigned aoff = (unsigned)(wm * 16384 + l15 * 128);
  const unsigned boff = (unsigned)(32768 + wn * 8192 + l15 * 128);
  const unsigned so0  = (unsigned)(((0 + g) ^ s7) * 16);
  const unsigned so1  = (unsigned)(((4 + g) ^ s7) * 16);

  const int bm256 = bm * 256, bn256 = bn * 256;
  const int srow = (wave * 4) * 8 + (lane >> 3);

  auto STAGE = [&](int s) {
    char* slot = lw + ((size_t)(s & 1) << 16);
    const int c0 = s * 64;
#pragma unroll
    for (int u = 0; u < 4; ++u) {
      const int row  = srow + u * 8;
      const int gcol = (lane & 7) ^ (row & 7);
      gload_lds16(aM + (size_t)(bm256 + row) * 4096 + c0 + gcol * 8,
                  slot + (wave * 4 + u) * 1024);
      gload_lds16(bM + (size_t)(bn256 + row) * 4096 + c0 + gcol * 8,
                  slot + 32768 + (wave * 4 + u) * 1024);
    }
  };

  f32x4 acc[8][4] = {};

  STAGE(0); VM0; BAR;
#pragma unroll 2
  for (int s = 0; s < 64; ++s) {
    if (s + 1 < 64) STAGE(s + 1);
    const unsigned sb = (unsigned)((s & 1) << 16);
    __builtin_amdgcn_s_setprio(1);
    TILE_BODY(sb);
    __builtin_amdgcn_s_setprio(0);
    LGKM0; VM0; BAR;
  }

  // epilogue
  const int md = (lane >> 4) * 4;
  const int r0 = bm256 + wm * 128;
  const int c0 = bn256 + wn * 64;
#pragma unroll
  for (int nf = 0; nf < 4; ++nf) {
    const int o = c0 + nf * 16 + l15;
    const float bs = bias2[o];
#pragma unroll
    for (int mf = 0; mf < 8; ++mf) {
      const int t_ = r0 + mf * 16 + md;
#pragma unroll
      for (int r = 0; r < 4; ++r)
        out[(size_t)(t_ + r) * 2048 + o] = acc[mf][nf][r] + bs;
    }
  }
}

// ----------------------------- launcher ------------------------------------

extern "C" void kernel_launch(void* const* d_in, const int* in_sizes, int n_in,
                              void* d_out, int out_size, void* d_ws, size_t ws_size,
                              hipStream_t stream) {
  const float* pix  = (const float*)d_in[0];
  const float* w1   = (const float*)d_in[2];
  const float* b1   = (const float*)d_in[3];
  const float* w2   = (const float*)d_in[4];
  const float* b2   = (const float*)d_in[5];
  const float* cosx = (const float*)d_in[6];
  const float* sinx = (const float*)d_in[7];
  const float* cosy = (const float*)d_in[8];
  const float* siny = (const float*)d_in[9];
  float* out = (float*)d_out;

  _Float16* ws = (_Float16*)d_ws;
  const size_t PE_N  = (size_t)8192 * 4096;
  const size_t B1_N  = (size_t)1024 * KP1;
  _Float16* peM  = ws;
  _Float16* b1h  = peM + PE_N;
  _Float16* b2h  = b1h + B1_N;
  // total ws ~84 MB

  conv_w_kernel<<<dim3(2432 + 8192), dim3(256), 0, stream>>>(w1, w2, b1h, b2h);
  patch_gemm18<<<dim3(128, 4), dim3(512), 0, stream>>>(
      pix, b1h, b1, cosx, sinx, cosy, siny, peM);
  dense_gemm9<<<dim3(32, 8), dim3(512), 0, stream>>>(
      peM, b2h, b2, out);
}

// Round 19
// 264.189 us; speedup vs baseline: 1.0098x; 1.0098x over previous
//
#include <hip/hip_runtime.h>
#include <cstdint>

// ---------------------------------------------------------------------------
// NEO vision embeddings, MI355X (gfx950) — round 19: dense -> 128x256 tile,
// single 48KB slot, 2 blocks/CU (cross-block overlap); patch/conv = r17.
//   conv:  B1 f16 [1024][640], B2 f16 perm [2048][4096]
//   GEMM1: peM = merge(rope(gelu(pix @ B1^T + b1)))  (256^2 BK=64, r17)
//   GEMM2: out = peM[8192,4096] @ B2^T + b2  (128x256, BK=64, 1-slot, 2/CU)
// dense iter s: STAGE(s) [6 gload_lds/wave] ; VM0 [covered by co-resident
// block's body] ; BAR ; 2 ks-passes x {read a[4],b[4]; 16 MFMA} ; LGKM0 ; BAR.
// VGPR budget: acc 64 + frags 32 + addr ~25 <= 128 (2-block residency cliff).
// ---------------------------------------------------------------------------

using f16x8 = __attribute__((ext_vector_type(8))) _Float16;
using f16x4 = __attribute__((ext_vector_type(4))) _Float16;
using f32x4 = __attribute__((ext_vector_type(4))) float;

__device__ __forceinline__ void gload_lds16(const void* g, void* l) {
  __builtin_amdgcn_global_load_lds(
      reinterpret_cast<const __attribute__((address_space(1))) unsigned int*>(
          reinterpret_cast<uintptr_t>(g)),
      reinterpret_cast<__attribute__((address_space(3))) unsigned int*>(
          reinterpret_cast<uintptr_t>(l)),
      16, 0, 0);
}

#define BAR   asm volatile("s_barrier" ::: "memory")
#define LGKM0 asm volatile("s_waitcnt lgkmcnt(0)" ::: "memory")
#define VM0   asm volatile("s_waitcnt vmcnt(0)" ::: "memory")

#define KP 640   // padded K for GEMM1 (588 -> 640 = 10 x 64)

// -------------------------- weight conversion ------------------------------

__global__ void conv_w_kernel(const float* __restrict__ w1,
                              const float* __restrict__ w2,
                              _Float16* __restrict__ h1,
                              _Float16* __restrict__ h2) {
  const int bid = blockIdx.x;
  if (bid < 2560) {                                // b1: 1024*640
    int i = bid * 256 + threadIdx.x;
    int e = i / KP;
    int k = i - e * KP;
    float v = (k < 588) ? w1[(size_t)e * 588 + k] : 0.0f;
    h1[i] = (_Float16)v;
  } else {                                         // b2: 2048*1024 float4s
    int j = (bid - 2560) * 256 + threadIdx.x;
    int o = j >> 10;
    int e = j & 1023;
    const float4 v = *(const float4*)(w2 + (size_t)o * 4096 + e * 4);
    h2[(size_t)o * 4096 + e]        = (_Float16)v.x;
    h2[(size_t)o * 4096 + 1024 + e] = (_Float16)v.y;
    h2[(size_t)o * 4096 + 2048 + e] = (_Float16)v.z;
    h2[(size_t)o * 4096 + 3072 + e] = (_Float16)v.w;
  }
}

// ------------------------- patch GEMM body macros (r17) --------------------

#define MFMA16(I0, J0, AV, BV)                                                \
  _Pragma("unroll") for (int i_ = 0; i_ < 4; ++i_)                            \
  _Pragma("unroll") for (int j_ = 0; j_ < 2; ++j_)                            \
  _Pragma("unroll") for (int k_ = 0; k_ < 2; ++k_)                            \
      acc[(I0) + i_][(J0) + j_] = __builtin_amdgcn_mfma_f32_16x16x32_f16(     \
          AV[i_][k_], BV[j_][k_], acc[(I0) + i_][(J0) + j_], 0, 0, 0);

#define TILE_BODY(sb)                                                         \
  {                                                                           \
    f16x8 a0[4][2], a1[4][2], vb0[2][2], vb1[2][2];                           \
    _Pragma("unroll") for (int i = 0; i < 4; ++i) {                           \
      a0[i][0] = *(const f16x8*)(lbase + (sb) + aoff + i * 2048 + so0);       \
      a0[i][1] = *(const f16x8*)(lbase + (sb) + aoff + i * 2048 + so1);       \
    }                                                                         \
    _Pragma("unroll") for (int j = 0; j < 2; ++j) {                           \
      vb0[j][0] = *(const f16x8*)(lbase + (sb) + boff + j * 2048 + so0);      \
      vb0[j][1] = *(const f16x8*)(lbase + (sb) + boff + j * 2048 + so1);      \
    }                                                                         \
    MFMA16(0, 0, a0, vb0);                                                    \
    _Pragma("unroll") for (int j = 0; j < 2; ++j) {                           \
      vb1[j][0] = *(const f16x8*)(lbase + (sb) + boff + (2+j) * 2048 + so0);  \
      vb1[j][1] = *(const f16x8*)(lbase + (sb) + boff + (2+j) * 2048 + so1);  \
    }                                                                         \
    MFMA16(0, 2, a0, vb1);                                                    \
    _Pragma("unroll") for (int i = 0; i < 4; ++i) {                           \
      a1[i][0] = *(const f16x8*)(lbase + (sb) + aoff + (4+i) * 2048 + so0);   \
      a1[i][1] = *(const f16x8*)(lbase + (sb) + aoff + (4+i) * 2048 + so1);   \
    }                                                                         \
    MFMA16(4, 2, a1, vb1);                                                    \
    MFMA16(4, 0, a1, vb0);                                                    \
  }

// ---------- GEMM1: r17 exact (256^2, single 64KB slot, reg-staged A) -------

__global__ __launch_bounds__(512, 2) void patch_gemm17(
    const float* __restrict__ pix,
    const _Float16* __restrict__ b1w,
    const float* __restrict__ bias1,
    const float* __restrict__ cosx, const float* __restrict__ sinx,
    const float* __restrict__ cosy, const float* __restrict__ siny,
    _Float16* __restrict__ peM)
{
  __shared__ _Float16 lds[2][256][64];   // 64 KiB single slot [op][row][64]

  const int tid  = threadIdx.x;
  const int lane = tid & 63;
  const int wave = tid >> 6;
  const int wm = wave >> 2, wn = wave & 3;
  const int bm = blockIdx.x, bn = blockIdx.y;
  const int l15 = lane & 15;
  const int g   = lane >> 4;
  const int s7  = l15 & 7;

  const char* lbase = (const char*)lds;
  char*       lw    = (char*)lds;
  const unsigned aoff = (unsigned)(wm * 16384 + l15 * 128);
  const unsigned boff = (unsigned)(32768 + wn * 8192 + l15 * 128);
  const unsigned so0  = (unsigned)(((0 + g) ^ s7) * 16);
  const unsigned so1  = (unsigned)(((4 + g) ^ s7) * 16);

  const int bm256 = bm * 256, bn256 = bn * 256;
  const int srow = wave * 32 + (lane >> 3);        // B staging row base
  const int acol = lane & 15;                      // A f32 col16 within tile
  const int arw  = wave * 32 + (lane >> 4);        // A row base (per u: +4u)

  auto LOADA = [&](int s, float4 (&ar)[8]) {
    const bool full = (s < 9);
#pragma unroll
    for (int u = 0; u < 8; ++u) {
      const int row = arw + u * 4;
      const float* p = pix + (size_t)(bm256 + row) * 588 + s * 64 + acol * 4;
      if (full || acol < 3) ar[u] = *(const float4*)p;   // s=9: k<588 only
      else ar[u] = make_float4(0.f, 0.f, 0.f, 0.f);
    }
  };
  auto WRITEA = [&](float4 (&ar)[8]) {             // single slot: A region
    const int c   = acol >> 1;
    const int sub = acol & 1;
#pragma unroll
    for (int u = 0; u < 8; ++u) {
      const int row = arw + u * 4;
      f16x4 v;
      v[0] = (_Float16)ar[u].x; v[1] = (_Float16)ar[u].y;
      v[2] = (_Float16)ar[u].z; v[3] = (_Float16)ar[u].w;
      *(f16x4*)(lw + row * 128 + ((c ^ (row & 7)) * 16 + sub * 8)) = v;
    }
  };
  auto STAGE_B = [&](int s) {
    const int c0 = s * 64;
#pragma unroll
    for (int u = 0; u < 4; ++u) {
      const int row  = srow + u * 8;
      const int gcol = (lane & 7) ^ (row & 7);
      gload_lds16(b1w + (size_t)(bn256 + row) * KP + c0 + gcol * 8,
                  lw + 32768 + (wave * 4 + u) * 1024);
    }
  };

  f32x4 acc[8][4] = {};
  float4 areg[8];

  LOADA(0, areg);
  for (int s = 0; s < 10; ++s) {
    WRITEA(areg);               // dep-wait retires LOADA(s) (reorder-proof)
    STAGE_B(s);
    VM0;                        // only the 4 B gloads outstanding here
    LGKM0; BAR;
    if (s + 1 < 10) LOADA(s + 1, areg);   // covered by TILE_BODY data-flow
    __builtin_amdgcn_s_setprio(1);
    TILE_BODY(0u);
    __builtin_amdgcn_s_setprio(0);
    LGKM0; BAR;
  }

  // ---- epilogue: per-wave LDS transpose (16-row passes, 33 KB total) ------
  float* sw = (float*)(lw) + wave * (16 * 65);
  const int md = (lane >> 4) * 4;
  const int rq = lane & 3;          // e-quarter
  const int lr = lane >> 2;         // row within 16-group
#pragma unroll
  for (int p = 0; p < 8; ++p) {
#pragma unroll
    for (int r = 0; r < 4; ++r) {
      const int lrow = md + r;
#pragma unroll
      for (int nf = 0; nf < 4; ++nf)
        sw[lrow * 65 + nf * 16 + l15] = acc[p][nf][r];
    }
    {
      const int m   = bm256 + wm * 128 + p * 16 + lr;
      const int pid = m & 4095;
      const int yy = pid >> 6, xx = pid & 63;
      const int t  = (m >> 12) * 1024 + (yy >> 1) * 32 + (xx >> 1);
      const int pq = (yy & 1) * 2 + (xx & 1);
      const int e0 = bn256 + wn * 64 + rq * 16;
      const int h2 = (e0 >= 512) ? 1 : 0;
      const int idx0 = (h2 ? (e0 - 512) : e0) >> 1;      // mult of 8
      const int pos  = h2 ? yy : xx;
      const float* ct = (h2 ? cosy : cosx) + pos * 256 + idx0;
      const float* st = (h2 ? siny : sinx) + pos * 256 + idx0;
      const float4 c0 = *(const float4*)ct, c1 = *(const float4*)(ct + 4);
      const float4 s0 = *(const float4*)st, s1 = *(const float4*)(st + 4);
      const float4 b0 = *(const float4*)(bias1 + e0);
      const float4 b1 = *(const float4*)(bias1 + e0 + 4);
      const float4 b2 = *(const float4*)(bias1 + e0 + 8);
      const float4 b3 = *(const float4*)(bias1 + e0 + 12);
      const float bb[16] = {b0.x,b0.y,b0.z,b0.w, b1.x,b1.y,b1.z,b1.w,
                            b2.x,b2.y,b2.z,b2.w, b3.x,b3.y,b3.z,b3.w};
      float v[16];
#pragma unroll
      for (int j = 0; j < 16; ++j) {
        float x = sw[lr * 65 + rq * 16 + j] + bb[j];
        v[j] = 0.5f * x * (1.0f + erff(x * 0.70710678118654752f));
      }
      const float cc[8] = {c0.x,c0.y,c0.z,c0.w, c1.x,c1.y,c1.z,c1.w};
      const float ss[8] = {s0.x,s0.y,s0.z,s0.w, s1.x,s1.y,s1.z,s1.w};
      _Float16 o[16];
#pragma unroll
      for (int k = 0; k < 8; ++k) {
        o[2*k]   = (_Float16)(v[2*k] * cc[k] - v[2*k+1] * ss[k]);
        o[2*k+1] = (_Float16)(v[2*k] * ss[k] + v[2*k+1] * cc[k]);
      }
      _Float16* dst = peM + (size_t)t * 4096 + pq * 1024 + e0;
      *(f16x8*)dst       = *(const f16x8*)&o[0];
      *(f16x8*)(dst + 8) = *(const f16x8*)&o[8];
    }
  }
}

// ---------- GEMM2: 128x256 tile, 48KB single slot, 2 blocks/CU -------------

__global__ __launch_bounds__(512, 2) void dense_gemm19(
    const _Float16* __restrict__ aM,    // [8192][4096] merged pe
    const _Float16* __restrict__ bM,    // [2048][4096] permuted w2
    const float* __restrict__ bias2, float* __restrict__ out)
{
  __shared__ _Float16 lds[3][128][64];   // 48 KiB: A [128][64] | B [256][64]

  const int tid  = threadIdx.x;
  const int lane = tid & 63;
  const int wave = tid >> 6;
  const int wm = wave >> 2, wn = wave & 3;   // wm: M-half(64), wn: N-quarter(64)
  const int bm = blockIdx.x, bn = blockIdx.y;
  const int l15 = lane & 15;
  const int g   = lane >> 4;
  const int s7  = l15 & 7;

  const char* lbase = (const char*)lds;
  char*       lw    = (char*)lds;
  const unsigned aoff = (unsigned)(wm * 8192 + l15 * 128);
  const unsigned boff = (unsigned)(16384 + wn * 8192 + l15 * 128);
  const unsigned so0  = (unsigned)(((0 + g) ^ s7) * 16);
  const unsigned so1  = (unsigned)(((4 + g) ^ s7) * 16);

  const int bm128 = bm * 128, bn256 = bn * 256;
  const int sr8 = lane >> 3;          // row-in-8 for staging
  const int sc8 = lane & 7;           // chunk for staging

  auto STAGE = [&](int s) {
    const int c0 = s * 64;
    // A: 128 rows -> 2 instr/wave (8 rows each)
#pragma unroll
    for (int u = 0; u < 2; ++u) {
      const int row  = wave * 16 + u * 8 + sr8;
      const int gcol = sc8 ^ (row & 7);
      gload_lds16(aM + (size_t)(bm128 + row) * 4096 + c0 + gcol * 8,
                  lw + (wave * 2 + u) * 1024);
    }
    // B: 256 rows -> 4 instr/wave
#pragma unroll
    for (int u = 0; u < 4; ++u) {
      const int row  = wave * 32 + u * 8 + sr8;
      const int gcol = sc8 ^ (row & 7);
      gload_lds16(bM + (size_t)(bn256 + row) * 4096 + c0 + gcol * 8,
                  lw + 16384 + (wave * 4 + u) * 1024);
    }
  };

  f32x4 acc[4][4] = {};

  for (int s = 0; s < 64; ++s) {
    STAGE(s);
    VM0; BAR;
    __builtin_amdgcn_s_setprio(1);
#pragma unroll
    for (int ks = 0; ks < 2; ++ks) {
      const unsigned so = ks ? so1 : so0;
      f16x8 a[4], b[4];
#pragma unroll
      for (int i = 0; i < 4; ++i)
        a[i] = *(const f16x8*)(lbase + aoff + i * 2048 + so);
#pragma unroll
      for (int j = 0; j < 4; ++j)
        b[j] = *(const f16x8*)(lbase + boff + j * 2048 + so);
#pragma unroll
      for (int i = 0; i < 4; ++i)
#pragma unroll
        for (int j = 0; j < 4; ++j)
          acc[i][j] = __builtin_amdgcn_mfma_f32_16x16x32_f16(
              a[i], b[j], acc[i][j], 0, 0, 0);
    }
    __builtin_amdgcn_s_setprio(0);
    LGKM0; BAR;
  }

  // epilogue
  const int md = (lane >> 4) * 4;
  const int r0 = bm128 + wm * 64;
  const int c0 = bn256 + wn * 64;
#pragma unroll
  for (int nf = 0; nf < 4; ++nf) {
    const int o = c0 + nf * 16 + l15;
    const float bs = bias2[o];
#pragma unroll
    for (int mf = 0; mf < 4; ++mf) {
      const int t_ = r0 + mf * 16 + md;
#pragma unroll
      for (int r = 0; r < 4; ++r)
        out[(size_t)(t_ + r) * 2048 + o] = acc[mf][nf][r] + bs;
    }
  }
}

// ----------------------------- launcher ------------------------------------

extern "C" void kernel_launch(void* const* d_in, const int* in_sizes, int n_in,
                              void* d_out, int out_size, void* d_ws, size_t ws_size,
                              hipStream_t stream) {
  const float* pix  = (const float*)d_in[0];
  const float* w1   = (const float*)d_in[2];
  const float* b1   = (const float*)d_in[3];
  const float* w2   = (const float*)d_in[4];
  const float* b2   = (const float*)d_in[5];
  const float* cosx = (const float*)d_in[6];
  const float* sinx = (const float*)d_in[7];
  const float* cosy = (const float*)d_in[8];
  const float* siny = (const float*)d_in[9];
  float* out = (float*)d_out;

  _Float16* ws = (_Float16*)d_ws;
  const size_t PE_N  = (size_t)8192 * 4096;
  const size_t B1_N  = (size_t)1024 * KP;
  _Float16* peM  = ws;
  _Float16* b1h  = peM + PE_N;
  _Float16* b2h  = b1h + B1_N;
  // total ws ~84 MB

  conv_w_kernel<<<dim3(2560 + 8192), dim3(256), 0, stream>>>(w1, w2, b1h, b2h);
  patch_gemm17<<<dim3(128, 4), dim3(512), 0, stream>>>(
      pix, b1h, b1, cosx, sinx, cosy, siny, peM);
  dense_gemm19<<<dim3(64, 8), dim3(512), 0, stream>>>(
      peM, b2h, b2, out);
}

// Round 20
// 246.040 us; speedup vs baseline: 1.0843x; 1.0738x over previous
//
#include <hip/hip_runtime.h>
#include <cstdint>

// ---------------------------------------------------------------------------
// NEO vision embeddings, MI355X (gfx950) — round 20: r14 composition (best
// measured, 248.7us) + full issue-early/write-late split in patch (T14):
// VM0+WRITEA(s+1) moved from mid-body to end-of-body (full ~1280cy cover for
// the ~900cy HBM latency of LOADA/STAGE_B issued at iter top).
//   conv:  B1 f16 [1024][640], B2 f16 perm [2048][4096]
//   GEMM1: peM = merge(rope(gelu(pix @ B1^T + b1)))  (256^2 BK=64, dbuf)
//   GEMM2: out = peM[8192,4096] @ B2^T + b2          (256^2 BK=64, r9)
// ---------------------------------------------------------------------------

using f16x8 = __attribute__((ext_vector_type(8))) _Float16;
using f16x4 = __attribute__((ext_vector_type(4))) _Float16;
using f32x4 = __attribute__((ext_vector_type(4))) float;

__device__ __forceinline__ void gload_lds16(const void* g, void* l) {
  __builtin_amdgcn_global_load_lds(
      reinterpret_cast<const __attribute__((address_space(1))) unsigned int*>(
          reinterpret_cast<uintptr_t>(g)),
      reinterpret_cast<__attribute__((address_space(3))) unsigned int*>(
          reinterpret_cast<uintptr_t>(l)),
      16, 0, 0);
}

#define BAR   asm volatile("s_barrier" ::: "memory")
#define LGKM0 asm volatile("s_waitcnt lgkmcnt(0)" ::: "memory")
#define VM0   asm volatile("s_waitcnt vmcnt(0)" ::: "memory")

#define KP 640   // padded K for GEMM1 (588 -> 640 = 10 x 64)

// -------------------------- weight conversion ------------------------------

__global__ void conv_w_kernel(const float* __restrict__ w1,
                              const float* __restrict__ w2,
                              _Float16* __restrict__ h1,
                              _Float16* __restrict__ h2) {
  const int bid = blockIdx.x;
  if (bid < 2560) {                                // b1: 1024*640
    int i = bid * 256 + threadIdx.x;
    int e = i / KP;
    int k = i - e * KP;
    float v = (k < 588) ? w1[(size_t)e * 588 + k] : 0.0f;
    h1[i] = (_Float16)v;
  } else {                                         // b2: 2048*1024 float4s
    int j = (bid - 2560) * 256 + threadIdx.x;
    int o = j >> 10;
    int e = j & 1023;
    const float4 v = *(const float4*)(w2 + (size_t)o * 4096 + e * 4);
    h2[(size_t)o * 4096 + e]        = (_Float16)v.x;
    h2[(size_t)o * 4096 + 1024 + e] = (_Float16)v.y;
    h2[(size_t)o * 4096 + 2048 + e] = (_Float16)v.z;
    h2[(size_t)o * 4096 + 3072 + e] = (_Float16)v.w;
  }
}

// ------------------------- shared GEMM body macros -------------------------

#define MFMA16(I0, J0, AV, BV)                                                \
  _Pragma("unroll") for (int i_ = 0; i_ < 4; ++i_)                            \
  _Pragma("unroll") for (int j_ = 0; j_ < 2; ++j_)                            \
  _Pragma("unroll") for (int k_ = 0; k_ < 2; ++k_)                            \
      acc[(I0) + i_][(J0) + j_] = __builtin_amdgcn_mfma_f32_16x16x32_f16(     \
          AV[i_][k_], BV[j_][k_], acc[(I0) + i_][(J0) + j_], 0, 0, 0);

#define TILE_BODY(sb)                                                         \
  {                                                                           \
    f16x8 a0[4][2], a1[4][2], vb0[2][2], vb1[2][2];                           \
    _Pragma("unroll") for (int i = 0; i < 4; ++i) {                           \
      a0[i][0] = *(const f16x8*)(lbase + (sb) + aoff + i * 2048 + so0);       \
      a0[i][1] = *(const f16x8*)(lbase + (sb) + aoff + i * 2048 + so1);       \
    }                                                                         \
    _Pragma("unroll") for (int j = 0; j < 2; ++j) {                           \
      vb0[j][0] = *(const f16x8*)(lbase + (sb) + boff + j * 2048 + so0);      \
      vb0[j][1] = *(const f16x8*)(lbase + (sb) + boff + j * 2048 + so1);      \
    }                                                                         \
    MFMA16(0, 0, a0, vb0);                                                    \
    _Pragma("unroll") for (int j = 0; j < 2; ++j) {                           \
      vb1[j][0] = *(const f16x8*)(lbase + (sb) + boff + (2+j) * 2048 + so0);  \
      vb1[j][1] = *(const f16x8*)(lbase + (sb) + boff + (2+j) * 2048 + so1);  \
    }                                                                         \
    MFMA16(0, 2, a0, vb1);                                                    \
    _Pragma("unroll") for (int i = 0; i < 4; ++i) {                           \
      a1[i][0] = *(const f16x8*)(lbase + (sb) + aoff + (4+i) * 2048 + so0);   \
      a1[i][1] = *(const f16x8*)(lbase + (sb) + aoff + (4+i) * 2048 + so1);   \
    }                                                                         \
    MFMA16(4, 2, a1, vb1);                                                    \
    MFMA16(4, 0, a1, vb0);                                                    \
  }

// ------------------- GEMM1: r14 K-loop, write-late A staging ---------------

__global__ __launch_bounds__(512, 2) void patch_gemm20(
    const float* __restrict__ pix,
    const _Float16* __restrict__ b1w,
    const float* __restrict__ bias1,
    const float* __restrict__ cosx, const float* __restrict__ sinx,
    const float* __restrict__ cosy, const float* __restrict__ siny,
    _Float16* __restrict__ peM)
{
  __shared__ _Float16 lds[2][2][256][64];   // 128 KiB (double-buffered)

  const int tid  = threadIdx.x;
  const int lane = tid & 63;
  const int wave = tid >> 6;
  const int wm = wave >> 2, wn = wave & 3;
  const int bm = blockIdx.x, bn = blockIdx.y;
  const int l15 = lane & 15;
  const int g   = lane >> 4;
  const int s7  = l15 & 7;

  const char* lbase = (const char*)lds;
  char*       lw    = (char*)lds;
  const unsigned aoff = (unsigned)(wm * 16384 + l15 * 128);
  const unsigned boff = (unsigned)(32768 + wn * 8192 + l15 * 128);
  const unsigned so0  = (unsigned)(((0 + g) ^ s7) * 16);
  const unsigned so1  = (unsigned)(((4 + g) ^ s7) * 16);

  const int bm256 = bm * 256, bn256 = bn * 256;
  const int srow = wave * 32 + (lane >> 3);        // B staging row base
  const int acol = lane & 15;                      // A f32 col16 within tile
  const int arw  = wave * 32 + (lane >> 4);        // A row base (per u: +4u)

  auto LOADA = [&](int s, float4 (&ar)[8]) {
    const bool full = (s < 9);
#pragma unroll
    for (int u = 0; u < 8; ++u) {
      const int row = arw + u * 4;
      const float* p = pix + (size_t)(bm256 + row) * 588 + s * 64 + acol * 4;
      if (full || acol < 3) ar[u] = *(const float4*)p;   // s=9: k<588 only
      else ar[u] = make_float4(0.f, 0.f, 0.f, 0.f);
    }
  };
  auto WRITEA = [&](int s, float4 (&ar)[8]) {
    char* slot = lw + ((size_t)((s) & 1) << 16);
    const int c   = acol >> 1;
    const int sub = acol & 1;
#pragma unroll
    for (int u = 0; u < 8; ++u) {
      const int row = arw + u * 4;
      f16x4 v;
      v[0] = (_Float16)ar[u].x; v[1] = (_Float16)ar[u].y;
      v[2] = (_Float16)ar[u].z; v[3] = (_Float16)ar[u].w;
      *(f16x4*)(slot + row * 128 + ((c ^ (row & 7)) * 16 + sub * 8)) = v;
    }
  };
  auto STAGE_B = [&](int s) {
    char* slot = lw + ((size_t)((s) & 1) << 16);
    const int c0 = s * 64;
#pragma unroll
    for (int u = 0; u < 4; ++u) {
      const int row  = srow + u * 8;
      const int gcol = (lane & 7) ^ (row & 7);
      gload_lds16(b1w + (size_t)(bn256 + row) * KP + c0 + gcol * 8,
                  slot + 32768 + (wave * 4 + u) * 1024);
    }
  };

  f32x4 acc[8][4] = {};
  float4 areg[8];

  LOADA(0, areg); STAGE_B(0);
  VM0; WRITEA(0, areg); LGKM0; BAR;

  for (int s = 0; s < 10; ++s) {
    const unsigned sb = (unsigned)((s & 1) << 16);
    const bool st = (s + 1 < 10);
    if (st) { LOADA(s + 1, areg); STAGE_B(s + 1); }   // issue early (top)
    __builtin_amdgcn_s_setprio(1);
    TILE_BODY(sb);                                    // full 64-MFMA cover
    __builtin_amdgcn_s_setprio(0);
    if (st) { VM0; WRITEA(s + 1, areg); }             // write late (end)
    LGKM0; BAR;
  }

  // ---- epilogue: per-wave LDS transpose -> vectorized gelu/rope/store -----
  BAR;   // all waves done reading K-loop LDS before overwrite
  float* sw = (float*)(lw) + wave * (32 * 65);
  const int md = (lane >> 4) * 4;
  const int rq = lane & 3;          // e-quarter
  const int lr = lane >> 2;         // row within 16-group
#pragma unroll
  for (int p = 0; p < 4; ++p) {
    // scatter my acc slice (rows mf=2p,2p+1) into the wave region
#pragma unroll
    for (int i = 0; i < 2; ++i)
#pragma unroll
      for (int r = 0; r < 4; ++r) {
        const int lrow = i * 16 + md + r;
#pragma unroll
        for (int nf = 0; nf < 4; ++nf)
          sw[lrow * 65 + nf * 16 + l15] = acc[2 * p + i][nf][r];
      }
    // gather: thread owns 16 consecutive e for 2 rows
#pragma unroll
    for (int rr = 0; rr < 2; ++rr) {
      const int lrow = rr * 16 + lr;
      const int m   = bm256 + wm * 128 + p * 32 + lrow;
      const int pid = m & 4095;
      const int yy = pid >> 6, xx = pid & 63;
      const int t  = (m >> 12) * 1024 + (yy >> 1) * 32 + (xx >> 1);
      const int pq = (yy & 1) * 2 + (xx & 1);
      const int e0 = bn256 + wn * 64 + rq * 16;
      const int h2 = (e0 >= 512) ? 1 : 0;
      const int idx0 = (h2 ? (e0 - 512) : e0) >> 1;      // mult of 8
      const int pos  = h2 ? yy : xx;
      const float* ct = (h2 ? cosy : cosx) + pos * 256 + idx0;
      const float* st = (h2 ? siny : sinx) + pos * 256 + idx0;
      const float4 c0 = *(const float4*)ct, c1 = *(const float4*)(ct + 4);
      const float4 s0 = *(const float4*)st, s1 = *(const float4*)(st + 4);
      const float4 b0 = *(const float4*)(bias1 + e0);
      const float4 b1 = *(const float4*)(bias1 + e0 + 4);
      const float4 b2 = *(const float4*)(bias1 + e0 + 8);
      const float4 b3 = *(const float4*)(bias1 + e0 + 12);
      const float bb[16] = {b0.x,b0.y,b0.z,b0.w, b1.x,b1.y,b1.z,b1.w,
                            b2.x,b2.y,b2.z,b2.w, b3.x,b3.y,b3.z,b3.w};
      float v[16];
#pragma unroll
      for (int j = 0; j < 16; ++j) {
        float x = sw[lrow * 65 + rq * 16 + j] + bb[j];
        v[j] = 0.5f * x * (1.0f + erff(x * 0.70710678118654752f));
      }
      const float cc[8] = {c0.x,c0.y,c0.z,c0.w, c1.x,c1.y,c1.z,c1.w};
      const float ss[8] = {s0.x,s0.y,s0.z,s0.w, s1.x,s1.y,s1.z,s1.w};
      _Float16 o[16];
#pragma unroll
      for (int k = 0; k < 8; ++k) {
        o[2*k]   = (_Float16)(v[2*k] * cc[k] - v[2*k+1] * ss[k]);
        o[2*k+1] = (_Float16)(v[2*k] * ss[k] + v[2*k+1] * cc[k]);
      }
      _Float16* dst = peM + (size_t)t * 4096 + pq * 1024 + e0;
      *(f16x8*)dst       = *(const f16x8*)&o[0];
      *(f16x8*)(dst + 8) = *(const f16x8*)&o[8];
    }
  }
}

// ------------------- GEMM2: r9 exact (127.5 us, MfmaUtil 50%) --------------

__global__ __launch_bounds__(512, 2) void dense_gemm9(
    const _Float16* __restrict__ aM,    // [8192][4096] merged pe
    const _Float16* __restrict__ bM,    // [2048][4096] permuted w2
    const float* __restrict__ bias2, float* __restrict__ out)
{
  __shared__ _Float16 lds[2][2][256][64];   // 128 KiB

  const int tid  = threadIdx.x;
  const int lane = tid & 63;
  const int wave = tid >> 6;
  const int wm = wave >> 2, wn = wave & 3;
  const int bm = blockIdx.x, bn = blockIdx.y;
  const int l15 = lane & 15;
  const int g   = lane >> 4;
  const int s7  = l15 & 7;

  const char* lbase = (const char*)lds;
  char*       lw    = (char*)lds;
  const unsigned aoff = (unsigned)(wm * 16384 + l15 * 128);
  const unsigned boff = (unsigned)(32768 + wn * 8192 + l15 * 128);
  const unsigned so0  = (unsigned)(((0 + g) ^ s7) * 16);
  const unsigned so1  = (unsigned)(((4 + g) ^ s7) * 16);

  const int bm256 = bm * 256, bn256 = bn * 256;
  const int srow = (wave * 4) * 8 + (lane >> 3);

  auto STAGE = [&](int s) {
    char* slot = lw + ((size_t)(s & 1) << 16);
    const int c0 = s * 64;
#pragma unroll
    for (int u = 0; u < 4; ++u) {
      const int row  = srow + u * 8;
      const int gcol = (lane & 7) ^ (row & 7);
      gload_lds16(aM + (size_t)(bm256 + row) * 4096 + c0 + gcol * 8,
                  slot + (wave * 4 + u) * 1024);
      gload_lds16(bM + (size_t)(bn256 + row) * 4096 + c0 + gcol * 8,
                  slot + 32768 + (wave * 4 + u) * 1024);
    }
  };

  f32x4 acc[8][4] = {};

  STAGE(0); VM0; BAR;
#pragma unroll 2
  for (int s = 0; s < 64; ++s) {
    if (s + 1 < 64) STAGE(s + 1);
    const unsigned sb = (unsigned)((s & 1) << 16);
    __builtin_amdgcn_s_setprio(1);
    TILE_BODY(sb);
    __builtin_amdgcn_s_setprio(0);
    LGKM0; VM0; BAR;
  }

  // epilogue
  const int md = (lane >> 4) * 4;
  const int r0 = bm256 + wm * 128;
  const int c0 = bn256 + wn * 64;
#pragma unroll
  for (int nf = 0; nf < 4; ++nf) {
    const int o = c0 + nf * 16 + l15;
    const float bs = bias2[o];
#pragma unroll
    for (int mf = 0; mf < 8; ++mf) {
      const int t_ = r0 + mf * 16 + md;
#pragma unroll
      for (int r = 0; r < 4; ++r)
        out[(size_t)(t_ + r) * 2048 + o] = acc[mf][nf][r] + bs;
    }
  }
}

// ----------------------------- launcher ------------------------------------

extern "C" void kernel_launch(void* const* d_in, const int* in_sizes, int n_in,
                              void* d_out, int out_size, void* d_ws, size_t ws_size,
                              hipStream_t stream) {
  const float* pix  = (const float*)d_in[0];
  const float* w1   = (const float*)d_in[2];
  const float* b1   = (const float*)d_in[3];
  const float* w2   = (const float*)d_in[4];
  const float* b2   = (const float*)d_in[5];
  const float* cosx = (const float*)d_in[6];
  const float* sinx = (const float*)d_in[7];
  const float* cosy = (const float*)d_in[8];
  const float* siny = (const float*)d_in[9];
  float* out = (float*)d_out;

  _Float16* ws = (_Float16*)d_ws;
  const size_t PE_N  = (size_t)8192 * 4096;
  const size_t B1_N  = (size_t)1024 * KP;
  _Float16* peM  = ws;
  _Float16* b1h  = peM + PE_N;
  _Float16* b2h  = b1h + B1_N;
  // total ws ~84 MB

  conv_w_kernel<<<dim3(2560 + 8192), dim3(256), 0, stream>>>(w1, w2, b1h, b2h);
  patch_gemm20<<<dim3(128, 4), dim3(512), 0, stream>>>(
      pix, b1h, b1, cosx, sinx, cosy, siny, peM);
  dense_gemm9<<<dim3(32, 8), dim3(512), 0, stream>>>(
      peM, b2h, b2, out);
}